// Round 7
// baseline (264.162 us; speedup 1.0000x reference)
//
#include <hip/hip_runtime.h>
#include <math.h>

// ---------------------------------------------------------------------------
// Round 7 (= R6 with compile fix): xpath with 4x4 register blocking (64x64
// wave tiles), counted-vmcnt 3-buffer weight pipeline (T4), sigmoid-GELU.
// Fix vs R6: no static array of LDS pointers (hipcc "unsupported expression
// in static initializer") — single BUF[3*8192] + computed offsets.
//
//   prep:  proj_w/mw1/mw2 fp32->bf16 ; bias_table -> biasPb[h][n][lr][8] bf16
//   A: ln_qkv: LN(q,k,v) + window partition -> qw/kw/vw bf16 [512][128][256]
//   B: attn per (window,head), 40KB LDS, swizzled Ps/Vt, bf16 bias -> ao
//   X: xpath per WINDOW (512 blocks, 512 thr = 8 waves = 2Mx4N of 64x64 tiles)
//      40-step pipeline; step s: waitcnt vmcnt(2); s_barrier; stage s+2
//      (16KB slice via gl2lds); 16 MFMA from buf s%3.
//      LDS: BUF 3x16KB | XL 64KB | H1 32KB | RED 4KB = 148KB, 1 block/CU.
// ---------------------------------------------------------------------------

typedef __attribute__((ext_vector_type(8))) short short8;
typedef __attribute__((ext_vector_type(4))) short shortx4;
typedef __attribute__((ext_vector_type(4))) float floatx4;

#define MFMA16(a, b, c) __builtin_amdgcn_mfma_f32_16x16x32_bf16((a), (b), (c), 0, 0, 0)
#define ATT_SCALE 0.17677669529663689f /* 32^-0.5 */

#define WAITV2() asm volatile("s_waitcnt vmcnt(2)" ::: "memory")
#define WAITV0() asm volatile("s_waitcnt vmcnt(0)" ::: "memory")
#define LGKM0() asm volatile("s_waitcnt lgkmcnt(0)" ::: "memory")
#define BARSYNC()                       \
  do {                                  \
    __builtin_amdgcn_s_barrier();       \
    __builtin_amdgcn_sched_barrier(0);  \
  } while (0)

__device__ __forceinline__ short f2bf(float f) {
  unsigned u = __float_as_uint(f);
  u += 0x7fffu + ((u >> 16) & 1u);
  return (short)(u >> 16);
}
__device__ __forceinline__ float bf2f(short s) {
  return __uint_as_float(((unsigned)(unsigned short)s) << 16);
}
__device__ __forceinline__ void gl2lds(const short* g, short* l) {
  __builtin_amdgcn_global_load_lds((const __attribute__((address_space(1))) void*)(g),
                                   (__attribute__((address_space(3))) void*)(l), 16, 0, 0);
}

// ---------------------------------------------------------------------------
// prep kernels
// ---------------------------------------------------------------------------
__global__ void cvt_kernel(const float* __restrict__ src, short* __restrict__ dst, int n) {
  int i = blockIdx.x * 256 + threadIdx.x;
  if (i < n) dst[i] = f2bf(src[i]);
}

__global__ void biasprep_kernel(const float* __restrict__ table, short* __restrict__ biasPb) {
  int idx = blockIdx.x * 256 + threadIdx.x;  // [0, 131072)
  int h = idx >> 14;
  int n = (idx >> 7) & 127;
  int lr = (idx >> 3) & 15;
  int c = idx & 7;
  int m = 16 * c + lr;
  int t1 = n >> 6, h1 = (n >> 3) & 7, w1 = n & 7;
  int t2 = m >> 6, h2 = (m >> 3) & 7, w2 = m & 7;
  int ridx = (t1 - t2 + 1) * 225 + (h1 - h2 + 7) * 15 + (w1 - w2 + 7);
  biasPb[idx] = f2bf(table[ridx * 8 + h]);
}

// ---------------------------------------------------------------------------
// Kernel A: LN + window partition, fp32 -> bf16 window layout. One wave/token.
// ---------------------------------------------------------------------------
__global__ __launch_bounds__(256) void ln_qkv_kernel(
    const float* __restrict__ q, const float* __restrict__ k, const float* __restrict__ v,
    const float* __restrict__ gq, const float* __restrict__ bq,
    const float* __restrict__ gk, const float* __restrict__ bk,
    const float* __restrict__ gv, const float* __restrict__ bv,
    short* __restrict__ qw, short* __restrict__ kw, short* __restrict__ vw) {
  const int wv = threadIdx.x >> 6, l = threadIdx.x & 63;
  const int tok = blockIdx.x * 4 + wv;
  const int which = blockIdx.y;
  const float* src = (which == 0) ? q : ((which == 1) ? k : v);
  const float* gg  = (which == 0) ? gq : ((which == 1) ? gk : gv);
  const float* bb  = (which == 0) ? bq : ((which == 1) ? bk : bv);
  short* dst       = (which == 0) ? qw : ((which == 1) ? kw : vw);

  float4 xv = *(const float4*)(src + (size_t)tok * 256 + l * 4);
  float s1 = xv.x + xv.y + xv.z + xv.w;
  float s2 = xv.x * xv.x + xv.y * xv.y + xv.z * xv.z + xv.w * xv.w;
#pragma unroll
  for (int off = 1; off < 64; off <<= 1) {
    s1 += __shfl_xor(s1, off);
    s2 += __shfl_xor(s2, off);
  }
  float mean = s1 * (1.0f / 256.0f);
  float var = s2 * (1.0f / 256.0f) - mean * mean;
  float inv = rsqrtf(var + 1e-5f);

  int b_ = tok >> 15, rem = tok & 32767;
  int t = rem >> 12, hh = (rem >> 6) & 63, ww = rem & 63;
  int wi = ((b_ * 4 + (t >> 1)) * 8 + (hh >> 3)) * 8 + (ww >> 3);
  int n = ((t & 1) << 6) | ((hh & 7) << 3) | (ww & 7);

  float4 g4 = *(const float4*)(gg + l * 4);
  float4 b4 = *(const float4*)(bb + l * 4);
  shortx4 o;
  o[0] = f2bf((xv.x - mean) * inv * g4.x + b4.x);
  o[1] = f2bf((xv.y - mean) * inv * g4.y + b4.y);
  o[2] = f2bf((xv.z - mean) * inv * g4.z + b4.z);
  o[3] = f2bf((xv.w - mean) * inv * g4.w + b4.w);
  *(shortx4*)(dst + ((size_t)wi * 128 + n) * 256 + l * 4) = o;
}

// ---------------------------------------------------------------------------
// Kernel B: windowed attention, one block per (window, head), 4 waves, 40KB LDS.
// ---------------------------------------------------------------------------
__global__ __launch_bounds__(256, 4) void attn_kernel(
    const short* __restrict__ qw, const short* __restrict__ kw, const short* __restrict__ vw,
    const short* __restrict__ biasPb, short* __restrict__ ao) {
  __shared__ union SU {
    struct { short Qs[128][40]; short Ks[128][40]; } qk;
    short Ps[128 * 128];  // XOR-swizzled
  } su;
  __shared__ short Vt[32 * 128];  // V^T, XOR-swizzled

  const int wi = blockIdx.x, h = blockIdx.y, tid = threadIdx.x;
  const size_t base = (size_t)wi * 128 * 256 + h * 32;

#pragma unroll
  for (int i = 0; i < 2; ++i) {
    int idx = tid + 256 * i;        // 0..511
    int m = idx >> 2, c = idx & 3;  // token row, 8-elem unit
    *(short8*)&su.qk.Qs[m][c * 8] = *(const short8*)(qw + base + (size_t)m * 256 + c * 8);
    *(short8*)&su.qk.Ks[m][c * 8] = *(const short8*)(kw + base + (size_t)m * 256 + c * 8);
    short8 vv = *(const short8*)(vw + base + (size_t)m * 256 + c * 8);
#pragma unroll
    for (int e = 0; e < 8; ++e) {
      int d = c * 8 + e;
      Vt[d * 128 + (((m >> 3) ^ (d & 7)) << 3) + (m & 7)] = vv[e];
    }
  }
  __syncthreads();

  const int wvv = tid >> 6, l = tid & 63, lr = l & 15, g = l >> 4;
  const floatx4 zf = {0.f, 0.f, 0.f, 0.f};

  short8 aq0 = *(const short8*)&su.qk.Qs[32 * wvv + lr][g * 8];
  short8 aq1 = *(const short8*)&su.qk.Qs[32 * wvv + 16 + lr][g * 8];

  floatx4 s[2][8];
#pragma unroll
  for (int c = 0; c < 8; ++c) {
    short8 bk8 = *(const short8*)&su.qk.Ks[16 * c + lr][g * 8];
    s[0][c] = MFMA16(aq0, bk8, zf);
    s[1][c] = MFMA16(aq1, bk8, zf);
  }
  __syncthreads();  // Qs/Ks dead -> Ps region reusable

  const int lr7 = lr & 7;
#pragma unroll
  for (int r = 0; r < 2; ++r) {
#pragma unroll
    for (int j = 0; j < 4; ++j) {
      int n = 32 * wvv + 16 * r + 4 * g + j;
      short8 bv8 = *(const short8*)(biasPb + ((size_t)(h * 128 + n) * 16 + lr) * 8);
      float mx = -1e30f;
#pragma unroll
      for (int c = 0; c < 8; ++c) {
        float val = s[r][c][j] * ATT_SCALE + bf2f(bv8[c]);
        s[r][c][j] = val;
        mx = fmaxf(mx, val);
      }
#pragma unroll
      for (int off = 1; off < 16; off <<= 1) mx = fmaxf(mx, __shfl_xor(mx, off));
      float sum = 0.f;
#pragma unroll
      for (int c = 0; c < 8; ++c) {
        float e = __expf(s[r][c][j] - mx);
        s[r][c][j] = e;
        sum += e;
      }
#pragma unroll
      for (int off = 1; off < 16; off <<= 1) sum += __shfl_xor(sum, off);
      float invs = 1.0f / sum;
      int n7 = n & 7;
#pragma unroll
      for (int c = 0; c < 8; ++c) {
        int col = 16 * c + lr;
        su.Ps[n * 128 + (((col >> 3) ^ n7) << 3) + (col & 7)] = f2bf(s[r][c][j] * invs);
      }
    }
  }
  // each wave reads only its own 32 P rows below -> no barrier

  floatx4 o00 = zf, o01 = zf, o10 = zf, o11 = zf;
  const int ra0 = 32 * wvv + lr, ra1 = ra0 + 16;
#pragma unroll
  for (int ks = 0; ks < 4; ++ks) {
    int ulog = ks * 4 + g;
    short8 pa0 = *(const short8*)&su.Ps[ra0 * 128 + ((ulog ^ (ra0 & 7)) << 3)];
    short8 pa1 = *(const short8*)&su.Ps[ra1 * 128 + ((ulog ^ (ra1 & 7)) << 3)];
    short8 vb0 = *(const short8*)&Vt[lr * 128 + ((ulog ^ lr7) << 3)];
    short8 vb1 = *(const short8*)&Vt[(16 + lr) * 128 + ((ulog ^ lr7) << 3)];
    o00 = MFMA16(pa0, vb0, o00);
    o01 = MFMA16(pa0, vb1, o01);
    o10 = MFMA16(pa1, vb0, o10);
    o11 = MFMA16(pa1, vb1, o11);
  }
#pragma unroll
  for (int j = 0; j < 4; ++j) {
    int n0 = 32 * wvv + 4 * g + j;
    int n1 = n0 + 16;
    size_t rb0 = ((size_t)wi * 128 + n0) * 256 + h * 32;
    size_t rb1 = ((size_t)wi * 128 + n1) * 256 + h * 32;
    ao[rb0 + lr] = f2bf(o00[j]);
    ao[rb0 + 16 + lr] = f2bf(o01[j]);
    ao[rb1 + lr] = f2bf(o10[j]);
    ao[rb1 + 16 + lr] = f2bf(o11[j]);
  }
}

// ---------------------------------------------------------------------------
// Kernel X: fused x-path v3. One block per WINDOW, 512 thr = 8 waves (2M x 4N
// of 64x64 output tiles; 4x4 16x16 fragments per wave -> 2:1 MFMA:ds_read).
// 40 pipelined steps; 16KB weight slices; counted vmcnt(2) + raw barriers.
// Weight slice LDS placement (16B units): R=256/BK=32: p=(r>>3)*32+u*8+(r&7);
// R=128/BK=64: p=(r>>3)*64+u*8+(r&7)  -> B-frag reads are ~conflict-free.
// ---------------------------------------------------------------------------
__global__ __launch_bounds__(512, 2) void xpath_kernel(
    const short* __restrict__ ao, const short* __restrict__ wp,
    const float* __restrict__ proj_b, const float* __restrict__ vin,
    const float* __restrict__ g2, const float* __restrict__ b2,
    const short* __restrict__ w1, const float* __restrict__ mb1,
    const short* __restrict__ w2, const float* __restrict__ mb2,
    float* __restrict__ out) {
  __shared__ short BUF[3 * 8192];  // 3 x 16KB weight slice buffers
  __shared__ short XL[128 * 256];  // 64KB, XOR-swizzled
  __shared__ short H1[128 * 128];  // 32KB, XOR-swizzled
  __shared__ float2 RED[128][4];   // 4KB LN2 cross-wave partials

  const int tid = threadIdx.x;
  const int w = tid >> 6, l = tid & 63, lr = l & 15, g = l >> 4;
  const int wm = w >> 2, wn = w & 3;  // 2 x 4 wave grid
  const floatx4 zf = {0.f, 0.f, 0.f, 0.f};
  const int bx = blockIdx.x;  // window index
  const int wb = bx & 7, hb = (bx >> 3) & 7, tt2 = (bx >> 6) & 3, b_ = bx >> 8;

  // staging lane -> (row, unit) for the two slice geometries
  const int p0 = (w * 2) * 64 + l, p1 = p0 + 64;
  const int rA0 = ((p0 >> 5) << 3) | (p0 & 7), uA0 = (p0 >> 3) & 3;  // R256 BK32
  const int rA1 = ((p1 >> 5) << 3) | (p1 & 7), uA1 = (p1 >> 3) & 3;
  const int rB0 = ((p0 >> 6) << 3) | (p0 & 7), uB0 = (p0 >> 3) & 7;  // R128 BK64
  const int rB1 = ((p1 >> 6) << 3) | (p1 & 7), uB1 = (p1 >> 3) & 7;

  // A-fragment rows (per mt) and B col-tile read bases
  int ra[4], ra7[4];
#pragma unroll
  for (int mt = 0; mt < 4; ++mt) {
    ra[mt] = wm * 64 + mt * 16 + lr;
    ra7[mt] = ra[mt] & 7;
  }
  int cF[4], cQ[2];
#pragma unroll
  for (int nt = 0; nt < 4; ++nt) {
    int rb = wn * 64 + nt * 16 + lr;
    cF[nt] = ((rb >> 3) << 8) | ((rb & 7) << 3);
  }
#pragma unroll
  for (int nt = 0; nt < 2; ++nt) {
    int rb = wn * 32 + nt * 16 + lr;
    cQ[nt] = ((rb >> 3) << 9) | ((rb & 7) << 3);
  }

  auto stage_wp = [&](short* dst, int k0) {
    gl2lds(wp + (size_t)rA0 * 256 + k0 + uA0 * 8, dst + (w * 2) * 512);
    gl2lds(wp + (size_t)rA1 * 256 + k0 + uA1 * 8, dst + (w * 2 + 1) * 512);
  };
  auto stage_w1 = [&](short* dst, int qt, int k0) {
    gl2lds(w1 + (size_t)(qt * 128 + rB0) * 256 + k0 + uB0 * 8, dst + (w * 2) * 512);
    gl2lds(w1 + (size_t)(qt * 128 + rB1) * 256 + k0 + uB1 * 8, dst + (w * 2 + 1) * 512);
  };
  auto stage_w2 = [&](short* dst, int k) {
    gl2lds(w2 + (size_t)rA0 * 512 + k + uA0 * 8, dst + (w * 2) * 512);
    gl2lds(w2 + (size_t)rA1 * 512 + k + uA1 * 8, dst + (w * 2 + 1) * 512);
  };

  const short* aoB = ao + (size_t)bx * 128 * 256;

  // ---------------- P1: proj GEMM (8 steps, BK=32) ----------------
  floatx4 acc1[4][4];
#pragma unroll
  for (int mt = 0; mt < 4; ++mt)
#pragma unroll
    for (int nt = 0; nt < 4; ++nt) acc1[mt][nt] = zf;

  stage_wp(BUF, 0);
  stage_wp(BUF + 8192, 32);
  short8 a[2][4];
#pragma unroll
  for (int mt = 0; mt < 4; ++mt)
    a[0][mt] = *(const short8*)(aoB + (size_t)ra[mt] * 256 + g * 8);

#pragma unroll
  for (int s = 0; s < 8; ++s) {
    WAITV2();
    BARSYNC();
    if (s < 6) stage_wp(BUF + ((s + 2) % 3) * 8192, 32 * (s + 2));
    else if (s == 6) stage_w1(BUF + 2 * 8192, 0, 0);  // step 8 = mlp1 qt0 k0
    else stage_w1(BUF, 0, 64);                        // step 9 = mlp1 qt0 k1
    if (s < 7) {
#pragma unroll
      for (int mt = 0; mt < 4; ++mt)
        a[(s + 1) & 1][mt] =
            *(const short8*)(aoB + (size_t)ra[mt] * 256 + 32 * (s + 1) + g * 8);
    }
    const short* bb = BUF + (s % 3) * 8192;
    short8 b[4];
#pragma unroll
    for (int nt = 0; nt < 4; ++nt) b[nt] = *(const short8*)&bb[cF[nt] + (g << 6)];
#pragma unroll
    for (int mt = 0; mt < 4; ++mt)
#pragma unroll
      for (int nt = 0; nt < 4; ++nt)
        acc1[mt][nt] = MFMA16(a[s & 1][mt], b[nt], acc1[mt][nt]);
  }

  // ---- epilogue: x = acc1 + proj_b + v(residual); LN2 (cross-wave) -> XL ----
  {
    float pbv[4], g2v[4], b2v[4];
#pragma unroll
    for (int nt = 0; nt < 4; ++nt) {
      int col = wn * 64 + nt * 16 + lr;
      pbv[nt] = proj_b[col];
      g2v[nt] = g2[col];
      b2v[nt] = b2[col];
    }
#pragma unroll
    for (int mt = 0; mt < 4; ++mt) {
#pragma unroll
      for (int j = 0; j < 4; ++j) {
        int row = wm * 64 + mt * 16 + 4 * g + j;
        int t = tt2 * 2 + (row >> 6), hh = hb * 8 + ((row >> 3) & 7), ww2 = wb * 8 + (row & 7);
        size_t sidx = ((size_t)(b_ * 8 + t) * 64 + hh) * 64 + ww2;
        float s1 = 0.f, s2 = 0.f;
#pragma unroll
        for (int nt = 0; nt < 4; ++nt) {
          float val = acc1[mt][nt][j] + pbv[nt] + vin[sidx * 256 + wn * 64 + nt * 16 + lr];
          acc1[mt][nt][j] = val;  // acc1 becomes the x residual (xr)
          s1 += val;
          s2 += val * val;
        }
#pragma unroll
        for (int off = 1; off < 16; off <<= 1) {
          s1 += __shfl_xor(s1, off);
          s2 += __shfl_xor(s2, off);
        }
        if (lr == 0) RED[row][wn] = make_float2(s1, s2);
      }
    }
    LGKM0();
    BARSYNC();
#pragma unroll
    for (int mt = 0; mt < 4; ++mt) {
#pragma unroll
      for (int j = 0; j < 4; ++j) {
        int row = wm * 64 + mt * 16 + 4 * g + j;
        float2 r0 = RED[row][0], r1 = RED[row][1], r2 = RED[row][2], r3 = RED[row][3];
        float mean = (r0.x + r1.x + r2.x + r3.x) * (1.0f / 256.0f);
        float var = (r0.y + r1.y + r2.y + r3.y) * (1.0f / 256.0f) - mean * mean;
        float inv = rsqrtf(var + 1e-5f);
        int r7 = row & 7;
#pragma unroll
        for (int nt = 0; nt < 4; ++nt) {
          int col = wn * 64 + nt * 16 + lr;
          float xlv = (acc1[mt][nt][j] - mean) * inv * g2v[nt] + b2v[nt];
          int u = col >> 3;
          XL[row * 256 + (((u & 24) | ((u & 7) ^ r7)) << 3) + (col & 7)] = f2bf(xlv);
        }
      }
    }
    LGKM0();  // XL publishes at the next barrier (first mlp step's BARSYNC)
  }

  // ---------------- P2: MLP (32 steps: per qt {mlp1 x4 BK64, mlp2 x4 BK32}) --
  floatx4 acc3[4][4];
#pragma unroll
  for (int mt = 0; mt < 4; ++mt)
#pragma unroll
    for (int nt = 0; nt < 4; ++nt) acc3[mt][nt] = zf;

#pragma unroll 1
  for (int qt = 0; qt < 4; ++qt) {
    floatx4 acc2[4][2];
#pragma unroll
    for (int mt = 0; mt < 4; ++mt)
#pragma unroll
      for (int nt = 0; nt < 2; ++nt) acc2[mt][nt] = zf;
    float mb1v[2];

#pragma unroll
    for (int t = 0; t < 8; ++t) {
      if (qt == 3 && t == 7) { WAITV0(); } else { WAITV2(); }
      BARSYNC();
      const int sb = (2 + 2 * qt + t) % 3;
      const short* bb = BUF + sb * 8192;
      short* sd = BUF + ((sb + 2) % 3) * 8192;
      // stage step s+2
      if (t < 2) stage_w1(sd, qt, 64 * (t + 2));
      else if (t < 6) stage_w2(sd, qt * 128 + 32 * (t - 2));
      else if (qt < 3) stage_w1(sd, qt + 1, 64 * (t - 6));
      if (t == 0) {
#pragma unroll
        for (int nt = 0; nt < 2; ++nt) mb1v[nt] = mb1[qt * 128 + wn * 32 + nt * 16 + lr];
      }

      if (t < 4) {
        // mlp1: A from XL (k0 = 64t), B 2 col-tiles, 2 k-slices
#pragma unroll
        for (int ks = 0; ks < 2; ++ks) {
          short8 xa[4], xb[2];
#pragma unroll
          for (int mt = 0; mt < 4; ++mt)
            xa[mt] = *(const short8*)&XL[ra[mt] * 256 + 64 * t + (((4 * ks + g) ^ ra7[mt]) << 3)];
#pragma unroll
          for (int nt = 0; nt < 2; ++nt)
            xb[nt] = *(const short8*)&bb[cQ[nt] + ((4 * ks + g) << 6)];
#pragma unroll
          for (int mt = 0; mt < 4; ++mt)
#pragma unroll
            for (int nt = 0; nt < 2; ++nt)
              acc2[mt][nt] = MFMA16(xa[mt], xb[nt], acc2[mt][nt]);
        }
        if (t == 3) {
          // GELU (sigmoid-form tanh approx) -> H1
#pragma unroll
          for (int mt = 0; mt < 4; ++mt)
#pragma unroll
            for (int nt = 0; nt < 2; ++nt) {
              int col = wn * 32 + nt * 16 + lr;
              int u = col >> 3;
#pragma unroll
              for (int j = 0; j < 4; ++j) {
                int row = wm * 64 + mt * 16 + 4 * g + j;
                float xv = acc2[mt][nt][j] + mb1v[nt];
                float yy = 1.5957691216057308f * (xv + 0.044715f * xv * xv * xv);
                float sg = 1.0f / (1.0f + __expf(-yy));
                H1[row * 128 + (((u & 8) | ((u & 7) ^ (row & 7))) << 3) + (col & 7)] =
                    f2bf(xv * sg);
              }
            }
          LGKM0();  // H1 publishes at next step's BARSYNC
        }
      } else {
        // mlp2: A from H1 (k0 = 32*(t-4)), B 4 col-tiles, 1 k-slice
        const int u0 = 4 * (t - 4);
        short8 ha[4], hbv[4];
#pragma unroll
        for (int mt = 0; mt < 4; ++mt) {
          int u = u0 + g;
          ha[mt] = *(const short8*)&H1[ra[mt] * 128 + (((u & 8) | ((u & 7) ^ ra7[mt])) << 3)];
        }
#pragma unroll
        for (int nt = 0; nt < 4; ++nt) hbv[nt] = *(const short8*)&bb[cF[nt] + (g << 6)];
#pragma unroll
        for (int mt = 0; mt < 4; ++mt)
#pragma unroll
          for (int nt = 0; nt < 4; ++nt)
            acc3[mt][nt] = MFMA16(ha[mt], hbv[nt], acc3[mt][nt]);
      }
    }
  }

  // ---------------- final: out = x + mlp2 + mb2 ----------------
  float mb2v[4];
#pragma unroll
  for (int nt = 0; nt < 4; ++nt) mb2v[nt] = mb2[wn * 64 + nt * 16 + lr];
#pragma unroll
  for (int mt = 0; mt < 4; ++mt)
#pragma unroll
    for (int j = 0; j < 4; ++j) {
      int row = wm * 64 + mt * 16 + 4 * g + j;
      int t = tt2 * 2 + (row >> 6), hh = hb * 8 + ((row >> 3) & 7), ww2 = wb * 8 + (row & 7);
      size_t sidx = ((size_t)(b_ * 8 + t) * 64 + hh) * 64 + ww2;
#pragma unroll
      for (int nt = 0; nt < 4; ++nt)
        out[sidx * 256 + wn * 64 + nt * 16 + lr] =
            acc1[mt][nt][j] + acc3[mt][nt][j] + mb2v[nt];
    }
}

// ---------------------------------------------------------------------------
extern "C" void kernel_launch(void* const* d_in, const int* in_sizes, int n_in,
                              void* d_out, int out_size, void* d_ws, size_t ws_size,
                              hipStream_t stream) {
  const float* q = (const float*)d_in[0];
  const float* k = (const float*)d_in[1];
  const float* v = (const float*)d_in[2];
  const float* gq = (const float*)d_in[3];
  const float* bq = (const float*)d_in[4];
  const float* gk = (const float*)d_in[5];
  const float* bk = (const float*)d_in[6];
  const float* gv = (const float*)d_in[7];
  const float* bv = (const float*)d_in[8];
  const float* bias_table = (const float*)d_in[9];
  const float* proj_w = (const float*)d_in[10];
  const float* proj_b = (const float*)d_in[11];
  const float* g2 = (const float*)d_in[12];
  const float* b2 = (const float*)d_in[13];
  const float* mw1 = (const float*)d_in[14];
  const float* mb1 = (const float*)d_in[15];
  const float* mw2 = (const float*)d_in[16];
  const float* mb2 = (const float*)d_in[17];

  char* ws = (char*)d_ws;
  short* qw = (short*)(ws + 0);
  short* kw = (short*)(ws + 33554432);
  short* vw = (short*)(ws + 67108864);
  short* ao = (short*)(ws + 100663296);
  short* wp = (short*)(ws + 167772160);
  short* w1 = (short*)(ws + 167903232);
  short* w2 = (short*)(ws + 168165376);
  short* biasPb = (short*)(ws + 168427520);

  cvt_kernel<<<256, 256, 0, stream>>>(proj_w, wp, 65536);
  cvt_kernel<<<512, 256, 0, stream>>>(mw1, w1, 131072);
  cvt_kernel<<<512, 256, 0, stream>>>(mw2, w2, 131072);
  biasprep_kernel<<<512, 256, 0, stream>>>(bias_table, biasPb);

  ln_qkv_kernel<<<dim3(16384, 3), 256, 0, stream>>>(q, k, v, gq, bq, gk, bk, gv, bv, qw, kw, vw);

  attn_kernel<<<dim3(512, 8), 256, 0, stream>>>(qw, kw, vw, biasPb, ao);

  xpath_kernel<<<512, 512, 0, stream>>>(ao, wp, proj_b, v, g2, b2, w1, mb1, w2, mb2,
                                        (float*)d_out);
}

// Round 8
// 256.452 us; speedup vs baseline: 1.0301x; 1.0301x over previous
//
#include <hip/hip_runtime.h>
#include <math.h>

// ---------------------------------------------------------------------------
// Round 8: weight-stationary x-path. Three barrier-free GEMM kernels, each
// holding its full weight slice in LDS (128KB, swizzled, loaded once):
//   P : proj + bias + residual(v) + LN2  -> xbf (bf16), xln (bf16)
//   M1: mlp1-half + GELU                 -> h1 (bf16, [65536][512])
//   M2: mlp2-colhalf + bias + residual   -> out (fp32, spatial)
// Waves own 32 rows x all block cols; A-frags preloaded to VGPRs from global;
// inner loop = ds_read(B) + MFMA only. No inner barriers at all.
// attn / ln_qkv / prep unchanged (R5/R7 passing versions).
//
// Workspace layout (bytes):
//   qw   [0,          33554432)   xln overlays after attn
//   kw   [33554432,   67108864)   xbf overlays after attn
//   vw   [67108864,  100663296)   h1 overlays (h1 = [67108864, 134217728))
//   ao   [100663296, 134217728)   dead after P (h1 upper half overlays)
//   wp   [167772160, 167903232)
//   w1   [167903232, 168165376)
//   w2   [168165376, 168427520)
//   biasPb [168427520, 168689664)
// ---------------------------------------------------------------------------

typedef __attribute__((ext_vector_type(8))) short short8;
typedef __attribute__((ext_vector_type(4))) short shortx4;
typedef __attribute__((ext_vector_type(4))) float floatx4;

#define MFMA16(a, b, c) __builtin_amdgcn_mfma_f32_16x16x32_bf16((a), (b), (c), 0, 0, 0)
#define ATT_SCALE 0.17677669529663689f /* 32^-0.5 */

__device__ __forceinline__ short f2bf(float f) {
  unsigned u = __float_as_uint(f);
  u += 0x7fffu + ((u >> 16) & 1u);
  return (short)(u >> 16);
}
__device__ __forceinline__ float bf2f(short s) {
  return __uint_as_float(((unsigned)(unsigned short)s) << 16);
}

// ---------------------------------------------------------------------------
// prep kernels
// ---------------------------------------------------------------------------
__global__ void cvt_kernel(const float* __restrict__ src, short* __restrict__ dst, int n) {
  int i = blockIdx.x * 256 + threadIdx.x;
  if (i < n) dst[i] = f2bf(src[i]);
}

__global__ void biasprep_kernel(const float* __restrict__ table, short* __restrict__ biasPb) {
  int idx = blockIdx.x * 256 + threadIdx.x;  // [0, 131072)
  int h = idx >> 14;
  int n = (idx >> 7) & 127;
  int lr = (idx >> 3) & 15;
  int c = idx & 7;
  int m = 16 * c + lr;
  int t1 = n >> 6, h1 = (n >> 3) & 7, w1 = n & 7;
  int t2 = m >> 6, h2 = (m >> 3) & 7, w2 = m & 7;
  int ridx = (t1 - t2 + 1) * 225 + (h1 - h2 + 7) * 15 + (w1 - w2 + 7);
  biasPb[idx] = f2bf(table[ridx * 8 + h]);
}

// ---------------------------------------------------------------------------
// Kernel A: LN + window partition, fp32 -> bf16 window layout. One wave/token.
// ---------------------------------------------------------------------------
__global__ __launch_bounds__(256) void ln_qkv_kernel(
    const float* __restrict__ q, const float* __restrict__ k, const float* __restrict__ v,
    const float* __restrict__ gq, const float* __restrict__ bq,
    const float* __restrict__ gk, const float* __restrict__ bk,
    const float* __restrict__ gv, const float* __restrict__ bv,
    short* __restrict__ qw, short* __restrict__ kw, short* __restrict__ vw) {
  const int wv = threadIdx.x >> 6, l = threadIdx.x & 63;
  const int tok = blockIdx.x * 4 + wv;
  const int which = blockIdx.y;
  const float* src = (which == 0) ? q : ((which == 1) ? k : v);
  const float* gg  = (which == 0) ? gq : ((which == 1) ? gk : gv);
  const float* bb  = (which == 0) ? bq : ((which == 1) ? bk : bv);
  short* dst       = (which == 0) ? qw : ((which == 1) ? kw : vw);

  float4 xv = *(const float4*)(src + (size_t)tok * 256 + l * 4);
  float s1 = xv.x + xv.y + xv.z + xv.w;
  float s2 = xv.x * xv.x + xv.y * xv.y + xv.z * xv.z + xv.w * xv.w;
#pragma unroll
  for (int off = 1; off < 64; off <<= 1) {
    s1 += __shfl_xor(s1, off);
    s2 += __shfl_xor(s2, off);
  }
  float mean = s1 * (1.0f / 256.0f);
  float var = s2 * (1.0f / 256.0f) - mean * mean;
  float inv = rsqrtf(var + 1e-5f);

  int b_ = tok >> 15, rem = tok & 32767;
  int t = rem >> 12, hh = (rem >> 6) & 63, ww = rem & 63;
  int wi = ((b_ * 4 + (t >> 1)) * 8 + (hh >> 3)) * 8 + (ww >> 3);
  int n = ((t & 1) << 6) | ((hh & 7) << 3) | (ww & 7);

  float4 g4 = *(const float4*)(gg + l * 4);
  float4 b4 = *(const float4*)(bb + l * 4);
  shortx4 o;
  o[0] = f2bf((xv.x - mean) * inv * g4.x + b4.x);
  o[1] = f2bf((xv.y - mean) * inv * g4.y + b4.y);
  o[2] = f2bf((xv.z - mean) * inv * g4.z + b4.z);
  o[3] = f2bf((xv.w - mean) * inv * g4.w + b4.w);
  *(shortx4*)(dst + ((size_t)wi * 128 + n) * 256 + l * 4) = o;
}

// ---------------------------------------------------------------------------
// Kernel B: windowed attention, one block per (window, head), 4 waves, 40KB LDS.
// ---------------------------------------------------------------------------
__global__ __launch_bounds__(256, 4) void attn_kernel(
    const short* __restrict__ qw, const short* __restrict__ kw, const short* __restrict__ vw,
    const short* __restrict__ biasPb, short* __restrict__ ao) {
  __shared__ union SU {
    struct { short Qs[128][40]; short Ks[128][40]; } qk;
    short Ps[128 * 128];  // XOR-swizzled
  } su;
  __shared__ short Vt[32 * 128];  // V^T, XOR-swizzled

  const int wi = blockIdx.x, h = blockIdx.y, tid = threadIdx.x;
  const size_t base = (size_t)wi * 128 * 256 + h * 32;

#pragma unroll
  for (int i = 0; i < 2; ++i) {
    int idx = tid + 256 * i;        // 0..511
    int m = idx >> 2, c = idx & 3;  // token row, 8-elem unit
    *(short8*)&su.qk.Qs[m][c * 8] = *(const short8*)(qw + base + (size_t)m * 256 + c * 8);
    *(short8*)&su.qk.Ks[m][c * 8] = *(const short8*)(kw + base + (size_t)m * 256 + c * 8);
    short8 vv = *(const short8*)(vw + base + (size_t)m * 256 + c * 8);
#pragma unroll
    for (int e = 0; e < 8; ++e) {
      int d = c * 8 + e;
      Vt[d * 128 + (((m >> 3) ^ (d & 7)) << 3) + (m & 7)] = vv[e];
    }
  }
  __syncthreads();

  const int wvv = tid >> 6, l = tid & 63, lr = l & 15, g = l >> 4;
  const floatx4 zf = {0.f, 0.f, 0.f, 0.f};

  short8 aq0 = *(const short8*)&su.qk.Qs[32 * wvv + lr][g * 8];
  short8 aq1 = *(const short8*)&su.qk.Qs[32 * wvv + 16 + lr][g * 8];

  floatx4 s[2][8];
#pragma unroll
  for (int c = 0; c < 8; ++c) {
    short8 bk8 = *(const short8*)&su.qk.Ks[16 * c + lr][g * 8];
    s[0][c] = MFMA16(aq0, bk8, zf);
    s[1][c] = MFMA16(aq1, bk8, zf);
  }
  __syncthreads();  // Qs/Ks dead -> Ps region reusable

  const int lr7 = lr & 7;
#pragma unroll
  for (int r = 0; r < 2; ++r) {
#pragma unroll
    for (int j = 0; j < 4; ++j) {
      int n = 32 * wvv + 16 * r + 4 * g + j;
      short8 bv8 = *(const short8*)(biasPb + ((size_t)(h * 128 + n) * 16 + lr) * 8);
      float mx = -1e30f;
#pragma unroll
      for (int c = 0; c < 8; ++c) {
        float val = s[r][c][j] * ATT_SCALE + bf2f(bv8[c]);
        s[r][c][j] = val;
        mx = fmaxf(mx, val);
      }
#pragma unroll
      for (int off = 1; off < 16; off <<= 1) mx = fmaxf(mx, __shfl_xor(mx, off));
      float sum = 0.f;
#pragma unroll
      for (int c = 0; c < 8; ++c) {
        float e = __expf(s[r][c][j] - mx);
        s[r][c][j] = e;
        sum += e;
      }
#pragma unroll
      for (int off = 1; off < 16; off <<= 1) sum += __shfl_xor(sum, off);
      float invs = 1.0f / sum;
      int n7 = n & 7;
#pragma unroll
      for (int c = 0; c < 8; ++c) {
        int col = 16 * c + lr;
        su.Ps[n * 128 + (((col >> 3) ^ n7) << 3) + (col & 7)] = f2bf(s[r][c][j] * invs);
      }
    }
  }
  // each wave reads only its own 32 P rows below -> no barrier

  floatx4 o00 = zf, o01 = zf, o10 = zf, o11 = zf;
  const int ra0 = 32 * wvv + lr, ra1 = ra0 + 16;
#pragma unroll
  for (int ks = 0; ks < 4; ++ks) {
    int ulog = ks * 4 + g;
    short8 pa0 = *(const short8*)&su.Ps[ra0 * 128 + ((ulog ^ (ra0 & 7)) << 3)];
    short8 pa1 = *(const short8*)&su.Ps[ra1 * 128 + ((ulog ^ (ra1 & 7)) << 3)];
    short8 vb0 = *(const short8*)&Vt[lr * 128 + ((ulog ^ lr7) << 3)];
    short8 vb1 = *(const short8*)&Vt[(16 + lr) * 128 + ((ulog ^ lr7) << 3)];
    o00 = MFMA16(pa0, vb0, o00);
    o01 = MFMA16(pa0, vb1, o01);
    o10 = MFMA16(pa1, vb0, o10);
    o11 = MFMA16(pa1, vb1, o11);
  }
#pragma unroll
  for (int j = 0; j < 4; ++j) {
    int n0 = 32 * wvv + 4 * g + j;
    int n1 = n0 + 16;
    size_t rb0 = ((size_t)wi * 128 + n0) * 256 + h * 32;
    size_t rb1 = ((size_t)wi * 128 + n1) * 256 + h * 32;
    ao[rb0 + lr] = f2bf(o00[j]);
    ao[rb0 + 16 + lr] = f2bf(o01[j]);
    ao[rb1 + lr] = f2bf(o10[j]);
    ao[rb1 + 16 + lr] = f2bf(o11[j]);
  }
}

// ---------------------------------------------------------------------------
// Kernel P: weight-stationary proj + bias + residual(v) + LN2.
// Grid 256 x 512thr. LDS: wp[256][256] bf16 swizzled = 128KB, loaded once.
// Wave w owns rows bx*256 + w*32 .. +32 (window order). No inner barriers.
// ---------------------------------------------------------------------------
__global__ __launch_bounds__(512, 2) void projln_kernel(
    const short* __restrict__ ao, const short* __restrict__ wp,
    const float* __restrict__ proj_b, const float* __restrict__ vin,
    const float* __restrict__ g2, const float* __restrict__ b2,
    short* __restrict__ xbf, short* __restrict__ xln) {
  __shared__ short WS[256 * 256];  // 128KB: row=out-col, 32 units/row, u^(r&7)

  const int tid = threadIdx.x;
  const int w = tid >> 6, l = tid & 63, lr = l & 15, g = l >> 4;
  const floatx4 zf = {0.f, 0.f, 0.f, 0.f};

  // one-time weight stage (reg -> swizzled LDS)
#pragma unroll
  for (int c = 0; c < 16; ++c) {
    int idx = tid * 16 + c;  // 0..8191
    int r = idx >> 5, u = idx & 31;
    short8 vv = *(const short8*)(wp + (size_t)r * 256 + u * 8);
    *(short8*)&WS[r * 256 + ((u ^ (r & 7)) << 3)] = vv;
  }

  // A preload: 2 row-tiles x 8 k-chunks
  const int rowbase = blockIdx.x * 256 + w * 32;
  short8 a[2][8];
#pragma unroll
  for (int mt = 0; mt < 2; ++mt)
#pragma unroll
    for (int s = 0; s < 8; ++s)
      a[mt][s] = *(const short8*)(ao + (size_t)(rowbase + mt * 16 + lr) * 256 + s * 32 + g * 8);

  __syncthreads();  // weights visible; only barrier in the kernel

  floatx4 acc[2][16];
#pragma unroll
  for (int mt = 0; mt < 2; ++mt)
#pragma unroll
    for (int ct = 0; ct < 16; ++ct) acc[mt][ct] = zf;

#pragma unroll
  for (int s = 0; s < 8; ++s) {
#pragma unroll
    for (int ct = 0; ct < 16; ++ct) {
      int rb = ct * 16 + lr;
      short8 b = *(const short8*)&WS[rb * 256 + (((s * 4 + g) ^ (rb & 7)) << 3)];
      acc[0][ct] = MFMA16(a[0][s], b, acc[0][ct]);
      acc[1][ct] = MFMA16(a[1][s], b, acc[1][ct]);
    }
  }

  // epilogue: x = acc + pb + v; LN2 in-wave; write xbf + xln (window order)
  float pb[16], g2v[16], b2v[16];
#pragma unroll
  for (int ct = 0; ct < 16; ++ct) {
    int col = ct * 16 + lr;
    pb[ct] = proj_b[col];
    g2v[ct] = g2[col];
    b2v[ct] = b2[col];
  }
#pragma unroll
  for (int mt = 0; mt < 2; ++mt) {
#pragma unroll
    for (int j = 0; j < 4; ++j) {
      int wrow = rowbase + mt * 16 + 4 * g + j;
      int wi = wrow >> 7, n = wrow & 127;
      int wb = wi & 7, hb = (wi >> 3) & 7, tt = (wi >> 6) & 3, b_ = wi >> 8;
      int t = tt * 2 + (n >> 6), hh = hb * 8 + ((n >> 3) & 7), ww2 = wb * 8 + (n & 7);
      size_t sidx = ((size_t)(b_ * 8 + t) * 64 + hh) * 64 + ww2;
      float xv[16], s1 = 0.f, s2 = 0.f;
#pragma unroll
      for (int ct = 0; ct < 16; ++ct) {
        float val = acc[mt][ct][j] + pb[ct] + vin[sidx * 256 + ct * 16 + lr];
        xv[ct] = val;
        s1 += val;
        s2 += val * val;
      }
#pragma unroll
      for (int off = 1; off < 16; off <<= 1) {
        s1 += __shfl_xor(s1, off);
        s2 += __shfl_xor(s2, off);
      }
      float mean = s1 * (1.0f / 256.0f);
      float var = s2 * (1.0f / 256.0f) - mean * mean;
      float inv = rsqrtf(var + 1e-5f);
#pragma unroll
      for (int ct = 0; ct < 16; ++ct) {
        int col = ct * 16 + lr;
        xbf[(size_t)wrow * 256 + col] = f2bf(xv[ct]);
        xln[(size_t)wrow * 256 + col] = f2bf((xv[ct] - mean) * inv * g2v[ct] + b2v[ct]);
      }
    }
  }
}

// ---------------------------------------------------------------------------
// Kernel M1: weight-stationary mlp1-half + GELU -> h1 (bf16 [65536][512]).
// Grid (256, 2) x 512thr. LDS: w1-half [256][256] swizzled = 128KB.
// ---------------------------------------------------------------------------
__global__ __launch_bounds__(512, 2) void mlp1_kernel(
    const short* __restrict__ xln, const short* __restrict__ w1,
    const float* __restrict__ mb1, short* __restrict__ h1) {
  __shared__ short WS[256 * 256];  // 128KB

  const int tid = threadIdx.x;
  const int w = tid >> 6, l = tid & 63, lr = l & 15, g = l >> 4;
  const int half = blockIdx.y;
  const floatx4 zf = {0.f, 0.f, 0.f, 0.f};
  const short* w1h = w1 + (size_t)half * 256 * 256;

#pragma unroll
  for (int c = 0; c < 16; ++c) {
    int idx = tid * 16 + c;
    int r = idx >> 5, u = idx & 31;
    short8 vv = *(const short8*)(w1h + (size_t)r * 256 + u * 8);
    *(short8*)&WS[r * 256 + ((u ^ (r & 7)) << 3)] = vv;
  }

  const int rowbase = blockIdx.x * 256 + w * 32;
  short8 a[2][8];
#pragma unroll
  for (int mt = 0; mt < 2; ++mt)
#pragma unroll
    for (int s = 0; s < 8; ++s)
      a[mt][s] = *(const short8*)(xln + (size_t)(rowbase + mt * 16 + lr) * 256 + s * 32 + g * 8);

  __syncthreads();

  floatx4 acc[2][16];
#pragma unroll
  for (int mt = 0; mt < 2; ++mt)
#pragma unroll
    for (int ct = 0; ct < 16; ++ct) acc[mt][ct] = zf;

#pragma unroll
  for (int s = 0; s < 8; ++s) {
#pragma unroll
    for (int ct = 0; ct < 16; ++ct) {
      int rb = ct * 16 + lr;
      short8 b = *(const short8*)&WS[rb * 256 + (((s * 4 + g) ^ (rb & 7)) << 3)];
      acc[0][ct] = MFMA16(a[0][s], b, acc[0][ct]);
      acc[1][ct] = MFMA16(a[1][s], b, acc[1][ct]);
    }
  }

  float bias[16];
#pragma unroll
  for (int ct = 0; ct < 16; ++ct) bias[ct] = mb1[half * 256 + ct * 16 + lr];
#pragma unroll
  for (int mt = 0; mt < 2; ++mt) {
#pragma unroll
    for (int j = 0; j < 4; ++j) {
      int wrow = rowbase + mt * 16 + 4 * g + j;
#pragma unroll
      for (int ct = 0; ct < 16; ++ct) {
        float xv = acc[mt][ct][j] + bias[ct];
        float yy = 1.5957691216057308f * (xv + 0.044715f * xv * xv * xv);
        float sg = 1.0f / (1.0f + __expf(-yy));
        h1[(size_t)wrow * 512 + half * 256 + ct * 16 + lr] = f2bf(xv * sg);
      }
    }
  }
}

// ---------------------------------------------------------------------------
// Kernel M2: weight-stationary mlp2 col-half + bias + residual(xbf) -> out.
// Grid (256, 2) x 512thr. LDS: w2 rows [half*128..+128][512] swizzled = 128KB.
// K=512 done in two register passes (A 64 VGPRs at a time).
// ---------------------------------------------------------------------------
__global__ __launch_bounds__(512, 2) void mlp2_kernel(
    const short* __restrict__ h1, const short* __restrict__ w2,
    const float* __restrict__ mb2, const short* __restrict__ xbf,
    float* __restrict__ out) {
  __shared__ short WS[128 * 512];  // 128KB: 64 units/row, u^(r&7)

  const int tid = threadIdx.x;
  const int w = tid >> 6, l = tid & 63, lr = l & 15, g = l >> 4;
  const int half = blockIdx.y;
  const floatx4 zf = {0.f, 0.f, 0.f, 0.f};
  const short* w2h = w2 + (size_t)half * 128 * 512;

#pragma unroll
  for (int c = 0; c < 16; ++c) {
    int idx = tid * 16 + c;
    int r = idx >> 6, u = idx & 63;
    short8 vv = *(const short8*)(w2h + (size_t)r * 512 + u * 8);
    *(short8*)&WS[r * 512 + ((u ^ (r & 7)) << 3)] = vv;
  }
  __syncthreads();

  const int rowbase = blockIdx.x * 256 + w * 32;
  floatx4 acc[2][8];
#pragma unroll
  for (int mt = 0; mt < 2; ++mt)
#pragma unroll
    for (int ct = 0; ct < 8; ++ct) acc[mt][ct] = zf;

#pragma unroll
  for (int hk = 0; hk < 2; ++hk) {
    short8 a[2][8];
#pragma unroll
    for (int mt = 0; mt < 2; ++mt)
#pragma unroll
      for (int s = 0; s < 8; ++s)
        a[mt][s] = *(const short8*)(h1 + (size_t)(rowbase + mt * 16 + lr) * 512 +
                                    hk * 256 + s * 32 + g * 8);
#pragma unroll
    for (int s = 0; s < 8; ++s) {
      int S = hk * 8 + s;
#pragma unroll
      for (int ct = 0; ct < 8; ++ct) {
        int rb = ct * 16 + lr;
        short8 b = *(const short8*)&WS[rb * 512 + (((S * 4 + g) ^ (rb & 7)) << 3)];
        acc[0][ct] = MFMA16(a[0][s], b, acc[0][ct]);
        acc[1][ct] = MFMA16(a[1][s], b, acc[1][ct]);
      }
    }
  }

  float bias[8];
#pragma unroll
  for (int ct = 0; ct < 8; ++ct) bias[ct] = mb2[half * 128 + ct * 16 + lr];
#pragma unroll
  for (int mt = 0; mt < 2; ++mt) {
#pragma unroll
    for (int j = 0; j < 4; ++j) {
      int wrow = rowbase + mt * 16 + 4 * g + j;
      int wi = wrow >> 7, n = wrow & 127;
      int wb = wi & 7, hb = (wi >> 3) & 7, tt = (wi >> 6) & 3, b_ = wi >> 8;
      int t = tt * 2 + (n >> 6), hh = hb * 8 + ((n >> 3) & 7), ww2 = wb * 8 + (n & 7);
      size_t sidx = ((size_t)(b_ * 8 + t) * 64 + hh) * 64 + ww2;
#pragma unroll
      for (int ct = 0; ct < 8; ++ct) {
        int col = half * 128 + ct * 16 + lr;
        out[sidx * 256 + col] =
            bf2f(xbf[(size_t)wrow * 256 + col]) + acc[mt][ct][j] + bias[ct];
      }
    }
  }
}

// ---------------------------------------------------------------------------
extern "C" void kernel_launch(void* const* d_in, const int* in_sizes, int n_in,
                              void* d_out, int out_size, void* d_ws, size_t ws_size,
                              hipStream_t stream) {
  const float* q = (const float*)d_in[0];
  const float* k = (const float*)d_in[1];
  const float* v = (const float*)d_in[2];
  const float* gq = (const float*)d_in[3];
  const float* bq = (const float*)d_in[4];
  const float* gk = (const float*)d_in[5];
  const float* bk = (const float*)d_in[6];
  const float* gv = (const float*)d_in[7];
  const float* bv = (const float*)d_in[8];
  const float* bias_table = (const float*)d_in[9];
  const float* proj_w = (const float*)d_in[10];
  const float* proj_b = (const float*)d_in[11];
  const float* g2 = (const float*)d_in[12];
  const float* b2 = (const float*)d_in[13];
  const float* mw1 = (const float*)d_in[14];
  const float* mb1 = (const float*)d_in[15];
  const float* mw2 = (const float*)d_in[16];
  const float* mb2 = (const float*)d_in[17];

  char* ws = (char*)d_ws;
  short* qw = (short*)(ws + 0);
  short* kw = (short*)(ws + 33554432);
  short* vw = (short*)(ws + 67108864);
  short* ao = (short*)(ws + 100663296);
  short* xln = (short*)(ws + 0);         // over qw (dead after attn)
  short* xbf = (short*)(ws + 33554432);  // over kw (dead after attn)
  short* h1 = (short*)(ws + 67108864);   // over vw+ao (dead after attn / P)
  short* wp = (short*)(ws + 167772160);
  short* w1 = (short*)(ws + 167903232);
  short* w2 = (short*)(ws + 168165376);
  short* biasPb = (short*)(ws + 168427520);

  cvt_kernel<<<256, 256, 0, stream>>>(proj_w, wp, 65536);
  cvt_kernel<<<512, 256, 0, stream>>>(mw1, w1, 131072);
  cvt_kernel<<<512, 256, 0, stream>>>(mw2, w2, 131072);
  biasprep_kernel<<<512, 256, 0, stream>>>(bias_table, biasPb);

  ln_qkv_kernel<<<dim3(16384, 3), 256, 0, stream>>>(q, k, v, gq, bq, gk, bk, gv, bv, qw, kw, vw);

  attn_kernel<<<dim3(512, 8), 256, 0, stream>>>(qw, kw, vw, biasPb, ao);

  projln_kernel<<<256, 512, 0, stream>>>(ao, wp, proj_b, v, g2, b2, xbf, xln);

  mlp1_kernel<<<dim3(256, 2), 512, 0, stream>>>(xln, w1, mb1, h1);

  mlp2_kernel<<<dim3(256, 2), 512, 0, stream>>>(h1, w2, mb2, xbf, (float*)d_out);
}